// Round 7
// baseline (155.003 us; speedup 1.0000x reference)
//
#include <hip/hip_runtime.h>
#include <hip/hip_cooperative_groups.h>
#include <math.h>

namespace cg = cooperative_groups;

#define TWO_N 512
#define DM    256
#define NT    256
#define KS    8                      // K-split factor (32 dims per partial)
#define RSTRIDE (TWO_N * TWO_N)      // floats per partial matrix (1 MB)

// ws layout (bytes):
//   R[8]  : 8 x [512*512] float @ 0        (8 MB partial squared distances)
//   tsort : [512] float  @ 8 MB
//   inv   : [512] int    @ 8 MB + 2048
//   acc   : 64 x double, 128-B spaced (64*16 doubles) @ 8 MB + 4096
//   cnt   : unsigned     @ 8 MB + 12288
#define OFF_TSORT (8u << 20)
#define OFF_INV   ((8u << 20) + 2048)
#define OFF_ACC   ((8u << 20) + 4096)
#define OFF_CNT   ((8u << 20) + 12288)

#define ACC4(acc, A, B) { float _d;                      \
    _d = (A).x - (B).x; acc += _d * _d;                  \
    _d = (A).y - (B).y; acc += _d * _d;                  \
    _d = (A).z - (B).z; acc += _d * _d;                  \
    _d = (A).w - (B).w; acc += _d * _d; }

// Single cooperative kernel, 512 blocks x 256 threads (2 blocks/CU,
// LDS ~27 KB -> co-residency guaranteed).
// Phase A: blocks 0..511 = 64x64 dist tiles, 4x4 register blocking,
//          K-split 8 (R5-validated). Blocks 0,1 also rank-by-count
//          (R4/R5-validated). Block 0 zeroes acc slots + cnt.
// grid.sync()
// Phase B: block i = row i (R5/R6-validated rows pipeline), fused
//          finalize via 64-slot f64 atomics + counter (R1 pattern,
//          contention spread over 64 cache lines).
__global__ __launch_bounds__(NT) void supcr_coop(
    const float* __restrict__ E, const float* __restrict__ T,
    float* __restrict__ R, float* __restrict__ tsort, int* __restrict__ inv,
    double* __restrict__ acc, unsigned* __restrict__ cnt,
    float* __restrict__ out)
{
    cg::grid_group grid = cg::this_grid();
    const int bid = blockIdx.x;
    const int t   = threadIdx.x;

    __shared__ float4 As4[64 * 9];   // 64 rows x 8 float4, pad to 9
    __shared__ float4 Bs4[64 * 9];
    __shared__ float  Tsh[TWO_N];
    __shared__ float  ts[TWO_N];
    __shared__ float  Pe[TWO_N];
    __shared__ float  P[TWO_N];
    __shared__ float  wsum[8];
    __shared__ double red4[4];
    __shared__ int    isLast;

    // ================= Phase A =================
    {
        const int tile = bid >> 3, ks = bid & 7;
        const int it = tile >> 3, jt = tile & 7;
        const float4* __restrict__ E4 = reinterpret_cast<const float4*>(E);

        #pragma unroll
        for (int p = 0; p < 2; ++p) {            // coalesced staging
            const int idx = t + p * 256;
            const int r = idx >> 3, c4 = idx & 7;
            As4[r * 9 + c4] = E4[(it * 64 + r) * 64 + ks * 8 + c4];
            Bs4[r * 9 + c4] = E4[(jt * 64 + r) * 64 + ks * 8 + c4];
        }
        __syncthreads();

        const int tx = t & 15, ty = t >> 4;      // 16x16 thread grid
        float a2[4][4];
        #pragma unroll
        for (int u = 0; u < 4; ++u)
            #pragma unroll
            for (int v = 0; v < 4; ++v) a2[u][v] = 0.f;

        #pragma unroll
        for (int k4 = 0; k4 < 8; ++k4) {
            float4 a[4], b[4];
            #pragma unroll
            for (int u = 0; u < 4; ++u) a[u] = As4[(ty + 16 * u) * 9 + k4];
            #pragma unroll
            for (int v = 0; v < 4; ++v) b[v] = Bs4[(tx + 16 * v) * 9 + k4];
            #pragma unroll
            for (int u = 0; u < 4; ++u)
                #pragma unroll
                for (int v = 0; v < 4; ++v) ACC4(a2[u][v], a[u], b[v]);
        }

        float* __restrict__ Rp = R + (size_t)ks * RSTRIDE;
        #pragma unroll
        for (int u = 0; u < 4; ++u) {
            const int row = it * 64 + ty + 16 * u;
            #pragma unroll
            for (int v = 0; v < 4; ++v)
                Rp[row * TWO_N + jt * 64 + tx + 16 * v] = a2[u][v];
        }
    }

    if (bid == 0) {                  // zero reduction state (re-poisoned
        if (t < 64) acc[t * 16] = 0.0;           //  by harness each iter)
        if (t == 0) *cnt = 0u;
    }

    if (bid < 2) {                   // rank-by-count: 1 element / thread
        Tsh[t] = T[t]; Tsh[t + 256] = T[t + 256];
        __syncthreads();
        const int   e  = bid * 256 + t;
        const float te = Tsh[e];
        int rk = 0;
        const float4* Tsh4 = reinterpret_cast<const float4*>(Tsh);
        #pragma unroll 4
        for (int j4 = 0; j4 < TWO_N / 4; ++j4) {
            const float4 tv = Tsh4[j4];          // LDS broadcast
            const int b0 = 4 * j4;
            rk += (tv.x < te) || (tv.x == te && b0     < e);
            rk += (tv.y < te) || (tv.y == te && b0 + 1 < e);
            rk += (tv.z < te) || (tv.z == te && b0 + 2 < e);
            rk += (tv.w < te) || (tv.w == te && b0 + 3 < e);
        }
        tsort[rk] = te;  inv[e] = rk;
    }

    grid.sync();

    // ================= Phase B: row i = bid =================
    const int i    = bid;
    const int lane = t & 63, wid = t >> 6;       // 4 waves
    const int m0 = t, m1 = t + 256;

    const float ti  = T[i];
    const float tk0 = T[m0], tk1 = T[m1];
    ts[m0] = tsort[m0];  ts[m1] = tsort[m1];

    float d20 = 0.f, d21 = 0.f;
    #pragma unroll
    for (int p = 0; p < KS; ++p) {
        d20 += R[(size_t)p * RSTRIDE + (size_t)i * TWO_N + m0];
        d21 += R[(size_t)p * RSTRIDE + (size_t)i * TWO_N + m1];
    }
    const float rik0 = sqrtf(d20), rik1 = sqrtf(d21);
    const float e0 = (m0 == i) ? 0.f : __expf(-rik0);
    const float e1 = (m1 == i) ? 0.f : __expf(-rik1);
    Pe[inv[m0]] = e0;                // scatter into sorted order
    Pe[inv[m1]] = e1;
    __syncthreads();

    // wave-level inclusive scan of both halves (interleaved)
    float v0 = Pe[m0], v1 = Pe[m1];
    #pragma unroll
    for (int off = 1; off < 64; off <<= 1) {
        const float u0 = __shfl_up(v0, off, 64);
        const float u1 = __shfl_up(v1, off, 64);
        if (lane >= off) { v0 += u0; v1 += u1; }
    }
    if (lane == 63) { wsum[wid] = v0; wsum[4 + wid] = v1; }
    __syncthreads();

    float b0f = 0.f, tot = 0.f;
    #pragma unroll
    for (int w = 0; w < 4; ++w) {
        const float s = wsum[w];
        tot += s;
        if (w < wid) b0f += s;
    }
    float b1f = tot;                             // all of half 0
    #pragma unroll
    for (int w = 0; w < 4; ++w) {
        const float s = wsum[4 + w];
        tot += s;
        if (w < wid) b1f += s;
    }
    P[m0] = v0 + b0f;
    P[m1] = v1 + b1f;
    const float Stot = tot;
    __syncthreads();

    const int mi = inv[i];                       // scalar broadcast
    const int nl = mi + 1;
    const int nr = TWO_N - mi;
    const float th0 = fabsf(ti - tk0);
    const float th1 = fabsf(ti - tk1);

    // 4 binary-search chains interleaved (left/right x item0/item1)
    int pos0 = 0, pr0 = 0, pos1 = 0, pr1 = 0;
    #pragma unroll
    for (int step = 512; step >= 1; step >>= 1) {
        const int a0 = pos0 + step, c0 = pr0 + step;
        const int a1 = pos1 + step, c1 = pr1 + step;
        if (a0 <= nl && fabsf(ti - ts[a0 - 1])      >= th0) pos0 = a0;
        if (c0 <= nr && fabsf(ti - ts[mi + c0 - 1]) <  th0) pr0  = c0;
        if (a1 <= nl && fabsf(ti - ts[a1 - 1])      >= th1) pos1 = a1;
        if (c1 <= nr && fabsf(ti - ts[mi + c1 - 1]) <  th1) pr1  = c1;
    }

    float lf = 0.f;
    if (m0 != i) {
        const int cl = nl - pos0, cr = pr0;      // interval [L, Rr]: d < th
        const int L = mi - cl + 1, Rr = mi + cr - 1;
        float inner = 0.f;
        if (Rr >= L) inner = P[Rr] - ((L > 0) ? P[L - 1] : 0.f);
        lf += -rik0 - logf(Stot - inner);
    }
    if (m1 != i) {
        const int cl = nl - pos1, cr = pr1;
        const int L = mi - cl + 1, Rr = mi + cr - 1;
        float inner = 0.f;
        if (Rr >= L) inner = P[Rr] - ((L > 0) ? P[L - 1] : 0.f);
        lf += -rik1 - logf(Stot - inner);
    }

    // block reduction: wave shfl + 4 partials
    double ld = (double)lf;
    #pragma unroll
    for (int off = 32; off > 0; off >>= 1) ld += __shfl_down(ld, off, 64);
    if (lane == 0) red4[wid] = ld;
    __syncthreads();

    // fused finalize: 64-slot spread atomics + counter (R1 pattern)
    if (t == 0) {
        const double bsum = red4[0] + red4[1] + red4[2] + red4[3];
        atomicAdd(&acc[(i & 63) * 16], bsum);    // <=8 blocks per line
        __threadfence();                         // order add before bump
        const unsigned old = atomicAdd(cnt, 1u);
        isLast = (old == TWO_N - 1) ? 1 : 0;
    }
    __syncthreads();
    if (isLast && t < 64) {
        double s = atomicAdd(&acc[t * 16], 0.0); // L2-coherent read
        #pragma unroll
        for (int off = 32; off > 0; off >>= 1) s += __shfl_down(s, off, 64);
        if (t == 0)
            out[0] = (float)(-s / (double)((long long)TWO_N * (TWO_N - 1)));
    }
}

extern "C" void kernel_launch(void* const* d_in, const int* in_sizes, int n_in,
                              void* d_out, int out_size, void* d_ws, size_t ws_size,
                              hipStream_t stream) {
    (void)in_sizes; (void)n_in; (void)out_size; (void)ws_size;
    const float* E = (const float*)d_in[0];   // [512,256] fp32
    const float* T = (const float*)d_in[1];   // [512]     fp32
    float* out = (float*)d_out;

    char* ws = (char*)d_ws;
    float*    R      = (float*)(ws);
    float*    tsortp = (float*)(ws + OFF_TSORT);
    int*      invp   = (int*)(ws + OFF_INV);
    double*   accp   = (double*)(ws + OFF_ACC);
    unsigned* cntp   = (unsigned*)(ws + OFF_CNT);

    void* args[] = { (void*)&E, (void*)&T, (void*)&R, (void*)&tsortp,
                     (void*)&invp, (void*)&accp, (void*)&cntp, (void*)&out };
    hipLaunchCooperativeKernel((const void*)supcr_coop, dim3(TWO_N), dim3(NT),
                               args, 0, stream);
}

// Round 9
// 105.476 us; speedup vs baseline: 1.4696x; 1.4696x over previous
//
#include <hip/hip_runtime.h>
#include <math.h>

#define TWO_N 512
#define DM    256
#define NT    256
#define KS    4                      // K-split factor (64 dims per partial)
#define RSTRIDE (TWO_N * TWO_N)      // floats per partial matrix (1 MB)

// ws layout (bytes):
//   R[4]  : 4 x [512*512] float @ 0      (4 MB partial squared distances)
//   tsort : [512] float  @ 4 MB
//   inv   : [512] int    @ 4 MB + 2048
//   acc   : 64 x double, 128-B spaced  @ 4 MB + 4096
//   cnt   : unsigned     @ 4 MB + 12288
#define OFF_TSORT (4u << 20)
#define OFF_INV   ((4u << 20) + 2048)
#define OFF_ACC   ((4u << 20) + 4096)
#define OFF_CNT   ((4u << 20) + 12288)

#define ACC4(acc, A, B) { float _d;                      \
    _d = (A).x - (B).x; acc += _d * _d;                  \
    _d = (A).y - (B).y; acc += _d * _d;                  \
    _d = (A).z - (B).z; acc += _d * _d;                  \
    _d = (A).w - (B).w; acc += _d * _d; }

// Blocks 0..255: 64x64 dist tiles, 4x4 register blocking, K-split 4
//   (64 dims each -> 512 LDS b128 reads/CU, ~2.6us; R5-validated math).
// Block 256: rank-by-count (R4/R5-validated, no barriers) + zero acc/cnt.
__global__ __launch_bounds__(NT) void supcr_dist_rank(
    const float* __restrict__ E, const float* __restrict__ T,
    float* __restrict__ R, float* __restrict__ tsort, int* __restrict__ inv,
    double* __restrict__ acc, unsigned* __restrict__ cnt)
{
    const int bid = blockIdx.x;
    const int t   = threadIdx.x;

    if (bid < 256) {
        __shared__ float4 As4[64 * 17];  // 64 rows x 16 float4, pad to 17
        __shared__ float4 Bs4[64 * 17];
        const int tile = bid >> 2, ks = bid & 3;
        const int it = tile >> 3, jt = tile & 7;
        const float4* __restrict__ E4 = reinterpret_cast<const float4*>(E);

        #pragma unroll
        for (int p = 0; p < 4; ++p) {            // coalesced staging
            const int idx = t + p * 256;
            const int r = idx >> 4, c4 = idx & 15;
            As4[r * 17 + c4] = E4[(it * 64 + r) * 64 + ks * 16 + c4];
            Bs4[r * 17 + c4] = E4[(jt * 64 + r) * 64 + ks * 16 + c4];
        }
        __syncthreads();

        const int tx = t & 15, ty = t >> 4;      // 16x16 thread grid
        float a2[4][4];
        #pragma unroll
        for (int u = 0; u < 4; ++u)
            #pragma unroll
            for (int v = 0; v < 4; ++v) a2[u][v] = 0.f;

        #pragma unroll
        for (int k4 = 0; k4 < 16; ++k4) {
            float4 a[4], b[4];
            #pragma unroll
            for (int u = 0; u < 4; ++u) a[u] = As4[(ty + 16 * u) * 17 + k4];
            #pragma unroll
            for (int v = 0; v < 4; ++v) b[v] = Bs4[(tx + 16 * v) * 17 + k4];
            #pragma unroll
            for (int u = 0; u < 4; ++u)
                #pragma unroll
                for (int v = 0; v < 4; ++v) ACC4(a2[u][v], a[u], b[v]);
        }

        float* __restrict__ Rp = R + (size_t)ks * RSTRIDE;
        #pragma unroll
        for (int u = 0; u < 4; ++u) {
            const int row = it * 64 + ty + 16 * u;
            #pragma unroll
            for (int v = 0; v < 4; ++v)
                Rp[row * TWO_N + jt * 64 + tx + 16 * v] = a2[u][v];
        }
    } else {
        // zero cross-block reduction state (visible via kernel boundary)
        if (t < 64) acc[t * 16] = 0.0;
        if (t == 0) *cnt = 0u;

        // rank-by-count: stable total order (value, then index)
        __shared__ float Tsh[TWO_N];
        Tsh[t] = T[t]; Tsh[t + 256] = T[t + 256];
        __syncthreads();

        const int ja = t, jb = t + 256;
        const float ta = Tsh[ja], tb = Tsh[jb];
        int rka = 0, rkb = 0;
        const float4* Tsh4 = reinterpret_cast<const float4*>(Tsh);
        #pragma unroll 4
        for (int j4 = 0; j4 < TWO_N / 4; ++j4) {
            const float4 tv = Tsh4[j4];          // LDS broadcast
            const int b0 = 4 * j4, b1 = b0 + 1, b2 = b0 + 2, b3 = b0 + 3;
            rka += (tv.x < ta) || (tv.x == ta && b0 < ja);
            rka += (tv.y < ta) || (tv.y == ta && b1 < ja);
            rka += (tv.z < ta) || (tv.z == ta && b2 < ja);
            rka += (tv.w < ta) || (tv.w == ta && b3 < ja);
            rkb += (tv.x < tb) || (tv.x == tb && b0 < jb);
            rkb += (tv.y < tb) || (tv.y == tb && b1 < jb);
            rkb += (tv.z < tb) || (tv.z == tb && b2 < jb);
            rkb += (tv.w < tb) || (tv.w == tb && b3 < jb);
        }
        tsort[rka] = ta;  inv[ja] = rka;
        tsort[rkb] = tb;  inv[jb] = rkb;
    }
}

// One block per row i, 256 threads, 2 raw indices each (m0=t, m1=t+256).
// Coalesced partial loads -> rik; LDS scatter via inv (zero uncoalesced
// global reads); R6 shfl scan + interleaved 4-chain search; fused finalize
// via 64-line spread atomics (R7-correctness-validated tail).
__global__ __launch_bounds__(NT) void supcr_rows(
    const float* __restrict__ T, const float* __restrict__ R,
    const float* __restrict__ tsort, const int* __restrict__ inv,
    double* __restrict__ acc, unsigned* __restrict__ cnt,
    float* __restrict__ out)
{
    const int i    = blockIdx.x;
    const int t    = threadIdx.x;
    const int lane = t & 63, wid = t >> 6;       // 4 waves

    __shared__ float  ts[TWO_N];
    __shared__ float  Pe[TWO_N];     // s~ scattered into sorted order
    __shared__ float  P[TWO_N];      // inclusive prefix sums (sorted order)
    __shared__ float  wsum[8];
    __shared__ double red4[4];
    __shared__ int    isLast;

    const float ti = T[i];
    const int m0 = t, m1 = t + 256;
    const float tk0 = T[m0], tk1 = T[m1];

    // ---- coalesced partial-sum loads -> distances ----
    float d20 = 0.f, d21 = 0.f;
    #pragma unroll
    for (int p = 0; p < KS; ++p) {
        d20 += R[(size_t)p * RSTRIDE + (size_t)i * TWO_N + m0];
        d21 += R[(size_t)p * RSTRIDE + (size_t)i * TWO_N + m1];
    }
    const float rik0 = sqrtf(d20), rik1 = sqrtf(d21);

    ts[m0] = tsort[m0];  ts[m1] = tsort[m1];
    Pe[inv[m0]] = (m0 == i) ? 0.f : __expf(-rik0);   // LDS scatter
    Pe[inv[m1]] = (m1 == i) ? 0.f : __expf(-rik1);
    __syncthreads();

    // ---- wave-level inclusive scan of both halves (interleaved) ----
    float v0 = Pe[m0], v1 = Pe[m1];
    #pragma unroll
    for (int off = 1; off < 64; off <<= 1) {
        const float u0 = __shfl_up(v0, off, 64);
        const float u1 = __shfl_up(v1, off, 64);
        if (lane >= off) { v0 += u0; v1 += u1; }
    }
    if (lane == 63) { wsum[wid] = v0; wsum[4 + wid] = v1; }
    __syncthreads();

    float b0f = 0.f, tot = 0.f;
    #pragma unroll
    for (int w = 0; w < 4; ++w) {
        const float s = wsum[w];
        tot += s;
        if (w < wid) b0f += s;
    }
    float b1f = tot;                             // all of half 0
    #pragma unroll
    for (int w = 0; w < 4; ++w) {
        const float s = wsum[4 + w];
        tot += s;
        if (w < wid) b1f += s;
    }
    P[m0] = v0 + b0f;
    P[m1] = v1 + b1f;
    const float Stot = tot;
    __syncthreads();

    const int mi = inv[i];                       // scalar broadcast
    const int nl = mi + 1;
    const int nr = TWO_N - mi;
    const float th0 = fabsf(ti - tk0);
    const float th1 = fabsf(ti - tk1);

    // ---- 4 binary-search chains interleaved (left/right x item0/item1) ----
    int pos0 = 0, pr0 = 0, pos1 = 0, pr1 = 0;
    #pragma unroll
    for (int step = 512; step >= 1; step >>= 1) {
        const int a0 = pos0 + step, c0 = pr0 + step;
        const int a1 = pos1 + step, c1 = pr1 + step;
        if (a0 <= nl && fabsf(ti - ts[a0 - 1])      >= th0) pos0 = a0;
        if (c0 <= nr && fabsf(ti - ts[mi + c0 - 1]) <  th0) pr0  = c0;
        if (a1 <= nl && fabsf(ti - ts[a1 - 1])      >= th1) pos1 = a1;
        if (c1 <= nr && fabsf(ti - ts[mi + c1 - 1]) <  th1) pr1  = c1;
    }

    float lf = 0.f;
    if (m0 != i) {
        const int cl = nl - pos0, cr = pr0;      // interval [L, Rr]: d < th
        const int L = mi - cl + 1, Rr = mi + cr - 1;
        float inner = 0.f;
        if (Rr >= L) inner = P[Rr] - ((L > 0) ? P[L - 1] : 0.f);
        lf += -rik0 - logf(Stot - inner);
    }
    if (m1 != i) {
        const int cl = nl - pos1, cr = pr1;
        const int L = mi - cl + 1, Rr = mi + cr - 1;
        float inner = 0.f;
        if (Rr >= L) inner = P[Rr] - ((L > 0) ? P[L - 1] : 0.f);
        lf += -rik1 - logf(Stot - inner);
    }

    // ---- block reduction: wave shfl + 4 partials ----
    double ld = (double)lf;
    #pragma unroll
    for (int off = 32; off > 0; off >>= 1) ld += __shfl_down(ld, off, 64);
    if (lane == 0) red4[wid] = ld;
    __syncthreads();

    // ---- fused finalize: 64-line spread atomics + counter ----
    if (t == 0) {
        const double bsum = red4[0] + red4[1] + red4[2] + red4[3];
        atomicAdd(&acc[(i & 63) * 16], bsum);    // <=8 blocks per line
        __threadfence();                         // order add before bump
        const unsigned old = atomicAdd(cnt, 1u);
        isLast = (old == TWO_N - 1) ? 1 : 0;
    }
    __syncthreads();
    if (isLast && t < 64) {
        double s = atomicAdd(&acc[t * 16], 0.0); // coherent read
        #pragma unroll
        for (int off = 32; off > 0; off >>= 1) s += __shfl_down(s, off, 64);
        if (t == 0)
            out[0] = (float)(-s / (double)((long long)TWO_N * (TWO_N - 1)));
    }
}

extern "C" void kernel_launch(void* const* d_in, const int* in_sizes, int n_in,
                              void* d_out, int out_size, void* d_ws, size_t ws_size,
                              hipStream_t stream) {
    (void)in_sizes; (void)n_in; (void)out_size; (void)ws_size;
    const float* E = (const float*)d_in[0];   // [512,256] fp32
    const float* T = (const float*)d_in[1];   // [512]     fp32
    float* out = (float*)d_out;

    char* ws = (char*)d_ws;
    float*    R      = (float*)(ws);
    float*    tsortp = (float*)(ws + OFF_TSORT);
    int*      invp   = (int*)(ws + OFF_INV);
    double*   accp   = (double*)(ws + OFF_ACC);
    unsigned* cntp   = (unsigned*)(ws + OFF_CNT);

    supcr_dist_rank<<<257, NT, 0, stream>>>(E, T, R, tsortp, invp, accp, cntp);
    supcr_rows<<<TWO_N, NT, 0, stream>>>(T, R, tsortp, invp, accp, cntp, out);
}

// Round 10
// 96.770 us; speedup vs baseline: 1.6018x; 1.0900x over previous
//
#include <hip/hip_runtime.h>
#include <math.h>

#define TWO_N 512
#define DM    256
#define NT    256

// ws layout (bytes):  (identical to the proven round-0/round-6 layout)
//   R     : [512*512] float  @ 0          (1 MB)
//   tsort : [512] float      @ 1048576
//   perm  : [512] int        @ 1050624
//   inv   : [512] int        @ 1052672
//   bsums : [512] double     @ 1054720
#define OFF_TSORT 1048576
#define OFF_PERM  1050624
#define OFF_INV   1052672
#define OFF_BSUM  1054720

#define ACC4(acc, A, B) { float _d;                      \
    _d = (A).x - (B).x; acc += _d * _d;                  \
    _d = (A).y - (B).y; acc += _d * _d;                  \
    _d = (A).z - (B).z; acc += _d * _d;                  \
    _d = (A).w - (B).w; acc += _d * _d; }

// Blocks 0..255: 32x32 distance tiles (squared-diff "GEMM"), coalesced —
//   byte-identical to the validated round-6 tiles.
// Block 256: rank-by-count (R4/R5/R7-validated; zero barriers, ~1us) emits
//   tsort/perm/inv — replaces the 45-round bitonic sort whose ~90 barriers
//   made it the serial pole (~7us > ~5us tile time) of this kernel.
__global__ __launch_bounds__(NT) void supcr_dist_rank(
    const float* __restrict__ E, const float* __restrict__ T,
    float* __restrict__ R, float* __restrict__ tsort,
    int* __restrict__ perm, int* __restrict__ inv)
{
    const int bid = blockIdx.x;
    const int t   = threadIdx.x;

    if (bid < 256) {
        __shared__ float4 As4[32 * 65];
        __shared__ float4 Bs4[32 * 65];
        const int it = bid >> 4, jt = bid & 15;
        const float4* __restrict__ E4 = reinterpret_cast<const float4*>(E);

        for (int idx = t; idx < 32 * 64; idx += NT) {    // coalesced staging
            const int row = idx >> 6, c4 = idx & 63;
            As4[row * 65 + c4] = E4[(it * 32 + row) * 64 + c4];
            Bs4[row * 65 + c4] = E4[(jt * 32 + row) * 64 + c4];
        }
        __syncthreads();

        const int ty = t >> 4, tx = t & 15;
        float a00 = 0.f, a01 = 0.f, a10 = 0.f, a11 = 0.f;
        #pragma unroll 8
        for (int k4 = 0; k4 < 64; ++k4) {
            const float4 a0 = As4[ty * 65 + k4];
            const float4 a1 = As4[(ty + 16) * 65 + k4];
            const float4 b0 = Bs4[tx * 65 + k4];
            const float4 b1 = Bs4[(tx + 16) * 65 + k4];
            ACC4(a00, a0, b0); ACC4(a01, a0, b1);
            ACC4(a10, a1, b0); ACC4(a11, a1, b1);
        }
        const int r0 = it * 32 + ty, r1 = r0 + 16;
        const int c0 = jt * 32 + tx, c1 = c0 + 16;
        R[r0 * TWO_N + c0] = sqrtf(a00);
        R[r0 * TWO_N + c1] = sqrtf(a01);
        R[r1 * TWO_N + c0] = sqrtf(a10);
        R[r1 * TWO_N + c1] = sqrtf(a11);
    } else {
        // rank-by-count: stable total order (value, then index).
        // rk(e) = #{j : t_j < t_e  or  (t_j == t_e and j < e)} — a bijection.
        __shared__ float Tsh[TWO_N];
        Tsh[t] = T[t]; Tsh[t + 256] = T[t + 256];
        __syncthreads();

        const int ja = t, jb = t + 256;
        const float ta = Tsh[ja], tb = Tsh[jb];
        int rka = 0, rkb = 0;
        const float4* Tsh4 = reinterpret_cast<const float4*>(Tsh);
        #pragma unroll 4
        for (int j4 = 0; j4 < TWO_N / 4; ++j4) {
            const float4 tv = Tsh4[j4];          // LDS broadcast (free)
            const int b0 = 4 * j4, b1 = b0 + 1, b2 = b0 + 2, b3 = b0 + 3;
            rka += (tv.x < ta) || (tv.x == ta && b0 < ja);
            rka += (tv.y < ta) || (tv.y == ta && b1 < ja);
            rka += (tv.z < ta) || (tv.z == ta && b2 < ja);
            rka += (tv.w < ta) || (tv.w == ta && b3 < ja);
            rkb += (tv.x < tb) || (tv.x == tb && b0 < jb);
            rkb += (tv.y < tb) || (tv.y == tb && b1 < jb);
            rkb += (tv.z < tb) || (tv.z == tb && b2 < jb);
            rkb += (tv.w < tb) || (tv.w == tb && b3 < jb);
        }
        tsort[rka] = ta;  perm[rka] = ja;  inv[ja] = rka;
        tsort[rkb] = tb;  perm[rkb] = jb;  inv[jb] = rkb;
    }
}

// byte-identical to round 6 (best measured: 76.5us total)
__global__ __launch_bounds__(NT) void supcr_rows(
    const float* __restrict__ T, const float* __restrict__ R,
    const float* __restrict__ tsort, const int* __restrict__ perm,
    const int* __restrict__ inv, double* __restrict__ bsums)
{
    const int i    = blockIdx.x;
    const int t    = threadIdx.x;
    const int lane = t & 63, wid = t >> 6;       // 4 waves

    __shared__ float  ts[TWO_N];
    __shared__ float  P[TWO_N];      // inclusive prefix sums (sorted order)
    __shared__ float  wsum[8];       // [0..3]=half0 wave totals, [4..7]=half1
    __shared__ double red4[4];

    const float ti = T[i];
    const int m0 = t, m1 = t + 256;

    // ---- stage + gather, values straight to registers ----
    ts[m0] = tsort[m0];  ts[m1] = tsort[m1];
    const int pj0 = perm[m0], pj1 = perm[m1];
    float v0 = (pj0 == i) ? 0.f : __expf(-R[(size_t)i * TWO_N + pj0]);
    float v1 = (pj1 == i) ? 0.f : __expf(-R[(size_t)i * TWO_N + pj1]);

    // ---- wave-level inclusive scan of both halves (interleaved) ----
    #pragma unroll
    for (int off = 1; off < 64; off <<= 1) {
        const float u0 = __shfl_up(v0, off, 64);
        const float u1 = __shfl_up(v1, off, 64);
        if (lane >= off) { v0 += u0; v1 += u1; }
    }
    if (lane == 63) { wsum[wid] = v0; wsum[4 + wid] = v1; }
    __syncthreads();

    float b0 = 0.f, tot = 0.f;
    #pragma unroll
    for (int w = 0; w < 4; ++w) {
        const float s = wsum[w];
        tot += s;
        if (w < wid) b0 += s;
    }
    float b1 = tot;                              // all of half 0
    #pragma unroll
    for (int w = 0; w < 4; ++w) {
        const float s = wsum[4 + w];
        tot += s;
        if (w < wid) b1 += s;
    }
    P[m0] = v0 + b0;
    P[m1] = v1 + b1;
    const float Stot = tot;
    __syncthreads();

    const int mi = inv[i];                       // scalar broadcast
    const int nl = mi + 1;
    const int nr = TWO_N - mi;

    const float theta0 = fabsf(ti - T[m0]);
    const float theta1 = fabsf(ti - T[m1]);
    const float rik0   = R[(size_t)i * TWO_N + m0];
    const float rik1   = R[(size_t)i * TWO_N + m1];

    // ---- 4 binary-search chains interleaved (left/right x item0/item1) ----
    int pos0 = 0, pr0 = 0, pos1 = 0, pr1 = 0;
    #pragma unroll
    for (int step = 512; step >= 1; step >>= 1) {
        const int a0 = pos0 + step, c0 = pr0 + step;
        const int a1 = pos1 + step, c1 = pr1 + step;
        if (a0 <= nl && fabsf(ti - ts[a0 - 1])      >= theta0) pos0 = a0;
        if (c0 <= nr && fabsf(ti - ts[mi + c0 - 1]) <  theta0) pr0  = c0;
        if (a1 <= nl && fabsf(ti - ts[a1 - 1])      >= theta1) pos1 = a1;
        if (c1 <= nr && fabsf(ti - ts[mi + c1 - 1]) <  theta1) pr1  = c1;
    }

    float lf = 0.f;
    if (m0 != i) {
        const int cl = nl - pos0, cr = pr0;      // interval [L, Rr]: d < theta
        const int L = mi - cl + 1, Rr = mi + cr - 1;
        float inner = 0.f;
        if (Rr >= L) inner = P[Rr] - ((L > 0) ? P[L - 1] : 0.f);
        lf += -rik0 - logf(Stot - inner);
    }
    if (m1 != i) {
        const int cl = nl - pos1, cr = pr1;
        const int L = mi - cl + 1, Rr = mi + cr - 1;
        float inner = 0.f;
        if (Rr >= L) inner = P[Rr] - ((L > 0) ? P[L - 1] : 0.f);
        lf += -rik1 - logf(Stot - inner);
    }

    // ---- block reduction: wave shfl + 4 partials ----
    double ld = (double)lf;
    #pragma unroll
    for (int off = 32; off > 0; off >>= 1) ld += __shfl_down(ld, off, 64);
    if (lane == 0) red4[wid] = ld;
    __syncthreads();
    if (t == 0) bsums[i] = red4[0] + red4[1] + red4[2] + red4[3];
}

// byte-identical to round 0/6
__global__ __launch_bounds__(TWO_N) void supcr_finalize(
    const double* __restrict__ bsums, float* __restrict__ out)
{
    __shared__ double red[TWO_N];
    const int t = threadIdx.x;
    red[t] = bsums[t];
    __syncthreads();
    for (int off = TWO_N / 2; off > 0; off >>= 1) {
        if (t < off) red[t] += red[t + off];
        __syncthreads();
    }
    if (t == 0)
        out[0] = (float)(-red[0] / (double)((long long)TWO_N * (TWO_N - 1)));
}

extern "C" void kernel_launch(void* const* d_in, const int* in_sizes, int n_in,
                              void* d_out, int out_size, void* d_ws, size_t ws_size,
                              hipStream_t stream) {
    (void)in_sizes; (void)n_in; (void)out_size; (void)ws_size;
    const float* E = (const float*)d_in[0];   // [512,256] fp32
    const float* T = (const float*)d_in[1];   // [512]     fp32
    float* out = (float*)d_out;

    char* ws = (char*)d_ws;
    float*  R      = (float*)(ws);
    float*  tsortp = (float*)(ws + OFF_TSORT);
    int*    permp  = (int*)(ws + OFF_PERM);
    int*    invp   = (int*)(ws + OFF_INV);
    double* bsums  = (double*)(ws + OFF_BSUM);

    supcr_dist_rank<<<257, NT, 0, stream>>>(E, T, R, tsortp, permp, invp);
    supcr_rows<<<TWO_N, NT, 0, stream>>>(T, R, tsortp, permp, invp, bsums);
    supcr_finalize<<<1, TWO_N, 0, stream>>>(bsums, out);
}

// Round 11
// 77.095 us; speedup vs baseline: 2.0106x; 1.2552x over previous
//
#include <hip/hip_runtime.h>
#include <math.h>

#define TWO_N 512
#define DM    256
#define NT    256

// ws layout (bytes):  (proven round-0/round-6 layout)
//   R     : [512*512] float  @ 0          (1 MB)
//   tsort : [512] float      @ 1048576
//   perm  : [512] int        @ 1050624
//   inv   : [512] int        @ 1052672
//   bsums : [512] double     @ 1054720
#define OFF_TSORT 1048576
#define OFF_PERM  1050624
#define OFF_INV   1052672
#define OFF_BSUM  1054720

#define ACC4(acc, A, B) { float _d;                      \
    _d = (A).x - (B).x; acc += _d * _d;                  \
    _d = (A).y - (B).y; acc += _d * _d;                  \
    _d = (A).z - (B).z; acc += _d * _d;                  \
    _d = (A).w - (B).w; acc += _d * _d; }

// Blocks 0..255: 32x32 distance tiles (squared-diff "GEMM"), coalesced.
// Block 256: bitonic sort of targets -> tsort/perm/inv.
// (byte-identical to the best-measured round-6 kernel, 76.5us)
__global__ __launch_bounds__(NT) void supcr_dist_sort(
    const float* __restrict__ E, const float* __restrict__ T,
    float* __restrict__ R, float* __restrict__ tsort,
    int* __restrict__ perm, int* __restrict__ inv)
{
    const int bid = blockIdx.x;
    const int t   = threadIdx.x;

    if (bid < 256) {
        __shared__ float4 As4[32 * 65];
        __shared__ float4 Bs4[32 * 65];
        const int it = bid >> 4, jt = bid & 15;
        const float4* __restrict__ E4 = reinterpret_cast<const float4*>(E);

        for (int idx = t; idx < 32 * 64; idx += NT) {    // coalesced staging
            const int row = idx >> 6, c4 = idx & 63;
            As4[row * 65 + c4] = E4[(it * 32 + row) * 64 + c4];
            Bs4[row * 65 + c4] = E4[(jt * 32 + row) * 64 + c4];
        }
        __syncthreads();

        const int ty = t >> 4, tx = t & 15;
        float a00 = 0.f, a01 = 0.f, a10 = 0.f, a11 = 0.f;
        #pragma unroll 8
        for (int k4 = 0; k4 < 64; ++k4) {
            const float4 a0 = As4[ty * 65 + k4];
            const float4 a1 = As4[(ty + 16) * 65 + k4];
            const float4 b0 = Bs4[tx * 65 + k4];
            const float4 b1 = Bs4[(tx + 16) * 65 + k4];
            ACC4(a00, a0, b0); ACC4(a01, a0, b1);
            ACC4(a10, a1, b0); ACC4(a11, a1, b1);
        }
        const int r0 = it * 32 + ty, r1 = r0 + 16;
        const int c0 = jt * 32 + tx, c1 = c0 + 16;
        R[r0 * TWO_N + c0] = sqrtf(a00);
        R[r0 * TWO_N + c1] = sqrtf(a01);
        R[r1 * TWO_N + c0] = sqrtf(a10);
        R[r1 * TWO_N + c1] = sqrtf(a11);
    } else {
        __shared__ float key[TWO_N];
        __shared__ int   pay[TWO_N];
        key[t] = T[t]; key[t + 256] = T[t + 256];
        pay[t] = t;    pay[t + 256] = t + 256;
        __syncthreads();
        for (int kk = 2; kk <= TWO_N; kk <<= 1) {
            for (int j = kk >> 1; j > 0; j >>= 1) {
                #pragma unroll
                for (int w = 0; w < 2; ++w) {
                    const int e = t + w * 256;
                    const int p = e ^ j;
                    if (p > e) {
                        const float a = key[e], b = key[p];
                        const int  pa = pay[e], pb = pay[p];
                        const bool up = ((e & kk) == 0);
                        if (up ? (a > b) : (a < b)) {
                            key[e] = b; key[p] = a;
                            pay[e] = pb; pay[p] = pa;
                        }
                    }
                }
                __syncthreads();
            }
        }
        tsort[t] = key[t];           tsort[t + 256] = key[t + 256];
        perm[t]  = pay[t];           perm[t + 256]  = pay[t + 256];
        inv[pay[t]] = t;             inv[pay[t + 256]] = t + 256;
    }
}

// One block per row i, 256 threads, 2 sorted slots each (m0=t, m1=t+256).
// 2-barrier wave shfl scan straight from the gather; four binary-search
// chains interleaved in ONE loop (4 independent ds_reads/step).
// (byte-identical to round 6)
__global__ __launch_bounds__(NT) void supcr_rows(
    const float* __restrict__ T, const float* __restrict__ R,
    const float* __restrict__ tsort, const int* __restrict__ perm,
    const int* __restrict__ inv, double* __restrict__ bsums)
{
    const int i    = blockIdx.x;
    const int t    = threadIdx.x;
    const int lane = t & 63, wid = t >> 6;       // 4 waves

    __shared__ float  ts[TWO_N];
    __shared__ float  P[TWO_N];      // inclusive prefix sums (sorted order)
    __shared__ float  wsum[8];       // [0..3]=half0 wave totals, [4..7]=half1
    __shared__ double red4[4];

    const float ti = T[i];
    const int m0 = t, m1 = t + 256;

    // ---- stage + gather, values straight to registers ----
    ts[m0] = tsort[m0];  ts[m1] = tsort[m1];
    const int pj0 = perm[m0], pj1 = perm[m1];
    float v0 = (pj0 == i) ? 0.f : __expf(-R[(size_t)i * TWO_N + pj0]);
    float v1 = (pj1 == i) ? 0.f : __expf(-R[(size_t)i * TWO_N + pj1]);

    // ---- wave-level inclusive scan of both halves (interleaved) ----
    #pragma unroll
    for (int off = 1; off < 64; off <<= 1) {
        const float u0 = __shfl_up(v0, off, 64);
        const float u1 = __shfl_up(v1, off, 64);
        if (lane >= off) { v0 += u0; v1 += u1; }
    }
    if (lane == 63) { wsum[wid] = v0; wsum[4 + wid] = v1; }
    __syncthreads();

    float b0 = 0.f, tot = 0.f;
    #pragma unroll
    for (int w = 0; w < 4; ++w) {
        const float s = wsum[w];
        tot += s;
        if (w < wid) b0 += s;
    }
    float b1 = tot;                              // all of half 0
    #pragma unroll
    for (int w = 0; w < 4; ++w) {
        const float s = wsum[4 + w];
        tot += s;
        if (w < wid) b1 += s;
    }
    P[m0] = v0 + b0;
    P[m1] = v1 + b1;
    const float Stot = tot;
    __syncthreads();

    const int mi = inv[i];                       // scalar broadcast
    const int nl = mi + 1;
    const int nr = TWO_N - mi;

    const float theta0 = fabsf(ti - T[m0]);
    const float theta1 = fabsf(ti - T[m1]);
    const float rik0   = R[(size_t)i * TWO_N + m0];
    const float rik1   = R[(size_t)i * TWO_N + m1];

    // ---- 4 binary-search chains interleaved (left/right x item0/item1) ----
    int pos0 = 0, pr0 = 0, pos1 = 0, pr1 = 0;
    #pragma unroll
    for (int step = 512; step >= 1; step >>= 1) {
        const int a0 = pos0 + step, c0 = pr0 + step;
        const int a1 = pos1 + step, c1 = pr1 + step;
        if (a0 <= nl && fabsf(ti - ts[a0 - 1])      >= theta0) pos0 = a0;
        if (c0 <= nr && fabsf(ti - ts[mi + c0 - 1]) <  theta0) pr0  = c0;
        if (a1 <= nl && fabsf(ti - ts[a1 - 1])      >= theta1) pos1 = a1;
        if (c1 <= nr && fabsf(ti - ts[mi + c1 - 1]) <  theta1) pr1  = c1;
    }

    float lf = 0.f;
    if (m0 != i) {
        const int cl = nl - pos0, cr = pr0;      // interval [L, Rr]: d < theta
        const int L = mi - cl + 1, Rr = mi + cr - 1;
        float inner = 0.f;
        if (Rr >= L) inner = P[Rr] - ((L > 0) ? P[L - 1] : 0.f);
        lf += -rik0 - logf(Stot - inner);
    }
    if (m1 != i) {
        const int cl = nl - pos1, cr = pr1;
        const int L = mi - cl + 1, Rr = mi + cr - 1;
        float inner = 0.f;
        if (Rr >= L) inner = P[Rr] - ((L > 0) ? P[L - 1] : 0.f);
        lf += -rik1 - logf(Stot - inner);
    }

    // ---- block reduction: wave shfl + 4 partials ----
    double ld = (double)lf;
    #pragma unroll
    for (int off = 32; off > 0; off >>= 1) ld += __shfl_down(ld, off, 64);
    if (lane == 0) red4[wid] = ld;
    __syncthreads();
    if (t == 0) bsums[i] = red4[0] + red4[1] + red4[2] + red4[3];
}

// byte-identical to round 0/6
__global__ __launch_bounds__(TWO_N) void supcr_finalize(
    const double* __restrict__ bsums, float* __restrict__ out)
{
    __shared__ double red[TWO_N];
    const int t = threadIdx.x;
    red[t] = bsums[t];
    __syncthreads();
    for (int off = TWO_N / 2; off > 0; off >>= 1) {
        if (t < off) red[t] += red[t + off];
        __syncthreads();
    }
    if (t == 0)
        out[0] = (float)(-red[0] / (double)((long long)TWO_N * (TWO_N - 1)));
}

extern "C" void kernel_launch(void* const* d_in, const int* in_sizes, int n_in,
                              void* d_out, int out_size, void* d_ws, size_t ws_size,
                              hipStream_t stream) {
    (void)in_sizes; (void)n_in; (void)out_size; (void)ws_size;
    const float* E = (const float*)d_in[0];   // [512,256] fp32
    const float* T = (const float*)d_in[1];   // [512]     fp32
    float* out = (float*)d_out;

    char* ws = (char*)d_ws;
    float*  R      = (float*)(ws);
    float*  tsortp = (float*)(ws + OFF_TSORT);
    int*    permp  = (int*)(ws + OFF_PERM);
    int*    invp   = (int*)(ws + OFF_INV);
    double* bsums  = (double*)(ws + OFF_BSUM);

    supcr_dist_sort<<<257, NT, 0, stream>>>(E, T, R, tsortp, permp, invp);
    supcr_rows<<<TWO_N, NT, 0, stream>>>(T, R, tsortp, permp, invp, bsums);
    supcr_finalize<<<1, TWO_N, 0, stream>>>(bsums, out);
}